// Round 1
// baseline (39155.676 us; speedup 1.0000x reference)
//
#include <hip/hip_runtime.h>

// ---------------------------------------------------------------------------
// BaseDecoderNetwork: 2-layer LSTM decoder + Luong attention, teacher-forced.
// B=1024, L=100 steps, H=O=256. All global I/O fp32.
// R4: enc fp16 in ws (L3-resident), nontemporal enc loads, fp16 weights+dot2.
// R5: latency-bound fix (VALUBusy 10%, Occ 48%, 4 waves/SIMD, 1 barrier
//     domain/CU). Re-tile: 512 blocks x 512 threads, 2 rows/block,
//     2 gate-rows/thread. __launch_bounds__(512,8) -> 4 blocks/CU =
//     32 waves/CU, 4 independent barrier groups hide per-stage L2/LLC
//     weight-load latency.
// ---------------------------------------------------------------------------

#define Bx 1024
#define Lq 100
#define Hd 256
#define Od 256
#define H4 1024

typedef _Float16 f16;
typedef _Float16 half2_t __attribute__((ext_vector_type(2)));
typedef _Float16 f16x4 __attribute__((ext_vector_type(4)));
typedef unsigned int uint;
typedef uint uint4v __attribute__((ext_vector_type(4)));

__device__ __forceinline__ float fdot2(half2_t a, half2_t b, float c) {
#if __has_builtin(__builtin_amdgcn_fdot2)
  return __builtin_amdgcn_fdot2(a, b, c, false);
#else
  return c + (float)a.x * (float)b.x + (float)a.y * (float)b.y;
#endif
}
// 8-wide f16 dot: w,a are 16B chunks holding 8 halves each.
__device__ __forceinline__ float dot8(float acc, float4 w, float4 a) {
  acc = fdot2(__builtin_bit_cast(half2_t, w.x), __builtin_bit_cast(half2_t, a.x), acc);
  acc = fdot2(__builtin_bit_cast(half2_t, w.y), __builtin_bit_cast(half2_t, a.y), acc);
  acc = fdot2(__builtin_bit_cast(half2_t, w.z), __builtin_bit_cast(half2_t, a.z), acc);
  acc = fdot2(__builtin_bit_cast(half2_t, w.w), __builtin_bit_cast(half2_t, a.w), acc);
  return acc;
}
__device__ __forceinline__ float sigmf(float x) { return 1.0f / (1.0f + __expf(-x)); }

// ---------------- Phase A kernels ----------------

// 4 LSTM weight mats (fp32) -> fp16 ws. seg0: Wih0 ctx-half (cols 256..511).
__global__ void k_cvt_lstm(const float* Wih0, const float* Whh0,
                           const float* Wih1, const float* Whh1, f16* dst) {
  int row = blockIdx.x, seg = row >> 10, r = row & 1023, c = threadIdx.x;
  const float* src; int stride, off;
  if (seg == 0)      { src = Wih0; stride = 512; off = 256; }
  else if (seg == 1) { src = Whh0; stride = 256; off = 0; }
  else if (seg == 2) { src = Wih1; stride = 256; off = 0; }
  else               { src = Whh1; stride = 256; off = 0; }
  dst[(size_t)seg * 262144 + (size_t)r * 256 + c] =
      (f16)src[(size_t)r * stride + off + c];
}

// Wconcat(256x512), Wout, Wcrit, WaT (transposed!) -> fp16 at wsW+1048576.
__global__ void k_cvt_small(const float* Wconcat, const float* Wout,
                            const float* Wcrit, const float* Wa, f16* dst) {
  int blk = blockIdx.x, seg = blk >> 8, r = blk & 255, c = threadIdx.x;
  if (seg == 0) {
    dst[(size_t)r * 512 + c]       = (f16)Wconcat[(size_t)r * 512 + c];
    dst[(size_t)r * 512 + 256 + c] = (f16)Wconcat[(size_t)r * 512 + 256 + c];
  } else if (seg == 1) {
    dst[131072 + (size_t)r * 256 + c] = (f16)Wout[(size_t)r * 256 + c];
  } else if (seg == 2) {
    dst[196608 + (size_t)r * 256 + c] = (f16)Wcrit[(size_t)r * 256 + c];
  } else {
    dst[262144 + (size_t)c * 256 + r] = (f16)Wa[(size_t)r * 256 + c];  // WaT
  }
}

__global__ void k_bias1(const float* bih1, const float* bhh1, float* b1) {
  int i = blockIdx.x * 256 + threadIdx.x;
  b1[i] = bih1[i] + bhh1[i];
}

__global__ void k_actions(const int* actions, float* out) {
  int i = blockIdx.x * 256 + threadIdx.x;
  out[i] = (float)actions[i];
}

// enc fp32 -> fp16 (26,214,400 elems; 4 per thread)
__global__ void k_cvt_enc(const float* enc, f16* dst) {
  size_t i = (size_t)blockIdx.x * 256 + threadIdx.x;  // float4 index
  const float4* s = (const float4*)enc;
  float4 v = s[i];
  f16x4 o = {(f16)v.x, (f16)v.y, (f16)v.z, (f16)v.w};
  *(f16x4*)(dst + 4 * i) = o;
}

// table0[a][j] = sum_k emb[a][k]*Wih0[j][k] + bih0[j] + bhh0[j]   (fp32)
__global__ void k_table0(const float* emb, const float* Wih0,
                         const float* bih0, const float* bhh0, float* t0) {
  __shared__ float shw[16][256];
  int j0 = blockIdx.x * 16, tid = threadIdx.x;
  for (int i = tid; i < 16 * 256; i += 256) {
    int r = i >> 8, c = i & 255;
    shw[r][c] = Wih0[(size_t)(j0 + r) * 512 + c];  // emb half: cols 0..255
  }
  __syncthreads();
  int a = tid;
  float acc[16];
#pragma unroll
  for (int r = 0; r < 16; r++) acc[r] = 0.f;
  for (int k = 0; k < 256; k++) {
    float e = emb[(size_t)a * 256 + k];
#pragma unroll
    for (int r = 0; r < 16; r++) acc[r] = fmaf(e, shw[r][k], acc[r]);
  }
#pragma unroll
  for (int r = 0; r < 16; r++)
    t0[(size_t)a * H4 + j0 + r] = acc[r] + bih0[j0 + r] + bhh0[j0 + r];
}

// ---------------- Phase B: fused sequential scan ----------------
// R5: 512 blocks x 512 threads; block owns batch rows b0, b0+1.
// 4 blocks/CU (32 waves) -> 4 independent barrier domains per CU.
template <bool E16>
__launch_bounds__(512, 8)
__global__ void k_seq(const float* enc, const f16* enc16,
                      const float* enc_h, const float* enc_c,
                      const int* actions, const float* bcrit,
                      const f16* wWih0c, const f16* wWhh0,
                      const f16* wWih1, const f16* wWhh1,
                      const f16* wWconcat, const f16* wWout, const f16* wWcrit,
                      const f16* wWaT,
                      const float* table0, const float* bias1, float* out) {
  const int tid = threadIdx.x;
  const int b0 = blockIdx.x * 2;

  __shared__ _Float16 sh_h0[2][264];    // fp16 activation copies (dot operands)
  __shared__ _Float16 sh_h1[2][264];
  __shared__ _Float16 sh_ctx[2][264];
  __shared__ _Float16 sh_ca[2][264];
  __shared__ _Float16 sh_logit[2][264];
  __shared__ _Float16 sh_v[2][264];     // v = h1 @ Wa (fp16 for dot2 score pass)
  __shared__ float sh_c0[2][256];       // fp32 cell-state masters
  __shared__ float sh_c1[2][256];
  __shared__ float sh_gates[2][H4];
  __shared__ float sh_sc[2][128];       // scores -> attn weights
  __shared__ float sh_pi[2][256];
  __shared__ float sh_red[2][20];
  __shared__ int sh_a[2];

  // --- init: h/c from enc_h/enc_c, ctx0 = mean_l enc (all 512 threads) ---
  {
    int bb = tid >> 8, h = tid & 255, gb = b0 + bb;
    sh_h0[bb][h] = (f16)enc_h[(size_t)(0 * Bx + gb) * Hd + h];
    sh_h1[bb][h] = (f16)enc_h[(size_t)(1 * Bx + gb) * Hd + h];
    sh_c0[bb][h] = enc_c[(size_t)(0 * Bx + gb) * Hd + h];
    sh_c1[bb][h] = enc_c[(size_t)(1 * Bx + gb) * Hd + h];
    const float* ep = enc + (size_t)gb * Lq * Hd + h;
    float s = 0.f;
#pragma unroll 4
    for (int l = 0; l < Lq; l++) s += __builtin_nontemporal_load(ep + (size_t)l * Hd);
    sh_ctx[bb][h] = (f16)(s * (1.0f / Lq));
  }
  __syncthreads();

  for (int t = 0; t < Lq; t++) {
    // S0: teacher-forced input index (x0 = 0)
    if (tid < 2) sh_a[tid] = (t == 0) ? 0 : actions[(size_t)(b0 + tid) * Lq + (t - 1)];
    __syncthreads();

    // S1: LSTM0 gates; thread owns gate rows j and j+512, both batch rows.
    {
      const int j = tid;
      const float4* w1a = (const float4*)(wWih0c + (size_t)j * Hd);
      const float4* w2a = (const float4*)(wWhh0 + (size_t)j * Hd);
      const float4* w1b = (const float4*)(wWih0c + (size_t)(j + 512) * Hd);
      const float4* w2b = (const float4*)(wWhh0 + (size_t)(j + 512) * Hd);
      float a00 = table0[(size_t)sh_a[0] * H4 + j];
      float a10 = table0[(size_t)sh_a[1] * H4 + j];
      float a01 = table0[(size_t)sh_a[0] * H4 + j + 512];
      float a11 = table0[(size_t)sh_a[1] * H4 + j + 512];
#pragma unroll 2
      for (int c = 0; c < 32; c++) {
        float4 x0 = *(const float4*)&sh_ctx[0][8 * c];
        float4 x1 = *(const float4*)&sh_ctx[1][8 * c];
        float4 wa = w1a[c], wc = w1b[c];
        a00 = dot8(a00, wa, x0); a10 = dot8(a10, wa, x1);
        a01 = dot8(a01, wc, x0); a11 = dot8(a11, wc, x1);
        float4 y0 = *(const float4*)&sh_h0[0][8 * c];
        float4 y1 = *(const float4*)&sh_h0[1][8 * c];
        float4 wb = w2a[c], wd = w2b[c];
        a00 = dot8(a00, wb, y0); a10 = dot8(a10, wb, y1);
        a01 = dot8(a01, wd, y0); a11 = dot8(a11, wd, y1);
      }
      sh_gates[0][j] = a00; sh_gates[1][j] = a10;
      sh_gates[0][j + 512] = a01; sh_gates[1][j + 512] = a11;
    }
    __syncthreads();

    // S1b: layer-0 cell update (gate order i,f,g,o) — all 512 threads.
    {
      int bb = tid >> 8, h = tid & 255;
      float gi = sh_gates[bb][h], gf = sh_gates[bb][h + 256];
      float gg = sh_gates[bb][h + 512], go = sh_gates[bb][h + 768];
      float c = sigmf(gf) * sh_c0[bb][h] + sigmf(gi) * tanhf(gg);
      sh_c0[bb][h] = c;
      sh_h0[bb][h] = (f16)(sigmf(go) * tanhf(c));
    }
    __syncthreads();

    // S2: LSTM1 gates = bias1 + h0.Wih1[j] + h1.Whh1[j]
    {
      const int j = tid;
      const float4* w1a = (const float4*)(wWih1 + (size_t)j * Hd);
      const float4* w2a = (const float4*)(wWhh1 + (size_t)j * Hd);
      const float4* w1b = (const float4*)(wWih1 + (size_t)(j + 512) * Hd);
      const float4* w2b = (const float4*)(wWhh1 + (size_t)(j + 512) * Hd);
      float bv0 = bias1[j], bv1 = bias1[j + 512];
      float a00 = bv0, a10 = bv0, a01 = bv1, a11 = bv1;
#pragma unroll 2
      for (int c = 0; c < 32; c++) {
        float4 x0 = *(const float4*)&sh_h0[0][8 * c];
        float4 x1 = *(const float4*)&sh_h0[1][8 * c];
        float4 wa = w1a[c], wc = w1b[c];
        a00 = dot8(a00, wa, x0); a10 = dot8(a10, wa, x1);
        a01 = dot8(a01, wc, x0); a11 = dot8(a11, wc, x1);
        float4 y0 = *(const float4*)&sh_h1[0][8 * c];
        float4 y1 = *(const float4*)&sh_h1[1][8 * c];
        float4 wb = w2a[c], wd = w2b[c];
        a00 = dot8(a00, wb, y0); a10 = dot8(a10, wb, y1);
        a01 = dot8(a01, wd, y0); a11 = dot8(a11, wd, y1);
      }
      sh_gates[0][j] = a00; sh_gates[1][j] = a10;
      sh_gates[0][j + 512] = a01; sh_gates[1][j + 512] = a11;
    }
    __syncthreads();

    // S2b: layer-1 cell update -> h1 ("out")
    {
      int bb = tid >> 8, h = tid & 255;
      float gi = sh_gates[bb][h], gf = sh_gates[bb][h + 256];
      float gg = sh_gates[bb][h + 512], go = sh_gates[bb][h + 768];
      float c = sigmf(gf) * sh_c1[bb][h] + sigmf(gi) * tanhf(gg);
      sh_c1[bb][h] = c;
      sh_h1[bb][h] = (f16)(sigmf(go) * tanhf(c));
    }
    __syncthreads();

    // S3a: v[bb][h] = sum_j h1[bb][j] * WaT[h][j]   (v = h1 @ Wa)
    {
      int bb = tid >> 8, h = tid & 255;
      const float4* w = (const float4*)(wWaT + (size_t)h * Hd);
      float s = 0.f;
#pragma unroll 4
      for (int c = 0; c < 32; c++) {
        float4 wv = w[c];
        float4 av = *(const float4*)&sh_h1[bb][8 * c];
        s = dot8(s, wv, av);
      }
      sh_v[bb][h] = (f16)s;
    }
    __syncthreads();

    // S3b: scores[bb][l] = v . enc[b,l,:]
    {
      int bb = tid >> 8, l = tid & 255;
      if (l < Lq) {
        float s = 0.f;
        if constexpr (E16) {
          const uint4v* ep = (const uint4v*)(enc16 + ((size_t)(b0 + bb) * Lq + l) * Hd);
#pragma unroll 4
          for (int c = 0; c < 32; c++) {
            uint4v u = __builtin_nontemporal_load(ep + c);
            float4 ev = __builtin_bit_cast(float4, u);
            float4 vv = *(const float4*)&sh_v[bb][8 * c];
            s = dot8(s, ev, vv);
          }
        } else {
          const float4* ep = (const float4*)(enc + ((size_t)(b0 + bb) * Lq + l) * Hd);
#pragma unroll 4
          for (int c = 0; c < 64; c++) {
            float4 u = ep[c];
            const f16* vv = &sh_v[bb][4 * c];
            s = fmaf(u.x, (float)vv[0], s);
            s = fmaf(u.y, (float)vv[1], s);
            s = fmaf(u.z, (float)vv[2], s);
            s = fmaf(u.w, (float)vv[3], s);
          }
        }
        sh_sc[bb][l] = s;
      }
    }
    __syncthreads();

    // S3c: softmax over l (one wave per batch row)
    if (tid < 128) {
      int bb = tid >> 6, lane = tid & 63;
      float v0 = (lane < Lq) ? sh_sc[bb][lane] : -1e30f;
      float v1 = (lane + 64 < Lq) ? sh_sc[bb][lane + 64] : -1e30f;
      float m = fmaxf(v0, v1);
      for (int off = 32; off; off >>= 1) m = fmaxf(m, __shfl_xor(m, off));
      float e0 = (lane < Lq) ? __expf(v0 - m) : 0.f;
      float e1 = (lane + 64 < Lq) ? __expf(v1 - m) : 0.f;
      float s = e0 + e1;
      for (int off = 32; off; off >>= 1) s += __shfl_xor(s, off);
      float inv = 1.0f / s;
      if (lane < Lq) sh_sc[bb][lane] = e0 * inv;
      if (lane + 64 < Lq) sh_sc[bb][lane + 64] = e1 * inv;
    }
    __syncthreads();

    // S4: ctx_att[bb][h] = sum_l attn * enc (coalesced on h)
    if constexpr (E16) {
      int bb = tid >> 8, hh = tid & 255;
      if (hh < 128) {  // each thread covers halves 2*hh, 2*hh+1
        const uint* ep = (const uint*)(enc16 + (size_t)(b0 + bb) * Lq * Hd) + hh;
        float s0 = 0.f, s1 = 0.f;
#pragma unroll 4
        for (int l = 0; l < Lq; l++) {
          uint u = __builtin_nontemporal_load(ep + (size_t)l * 128);
          half2_t hv = __builtin_bit_cast(half2_t, u);
          float a = sh_sc[bb][l];
          s0 = fmaf(a, (float)hv.x, s0);
          s1 = fmaf(a, (float)hv.y, s1);
        }
        half2_t r = {(f16)s0, (f16)s1};
        *(half2_t*)&sh_ca[bb][2 * hh] = r;
      }
    } else {
      int bb = tid >> 8, h = tid & 255;
      const float* ep = enc + (size_t)(b0 + bb) * Lq * Hd + h;
      float s = 0.f;
#pragma unroll 4
      for (int l = 0; l < Lq; l++)
        s = fmaf(sh_sc[bb][l], __builtin_nontemporal_load(ep + (size_t)l * Hd), s);
      sh_ca[bb][h] = (f16)s;
    }
    __syncthreads();

    // S5: new_ctx = tanh([h1, ctx_att] @ Wconcat.T)
    {
      int bb = tid >> 8, j = tid & 255;
      const float4* w = (const float4*)(wWconcat + (size_t)j * 512);
      float s = 0.f;
#pragma unroll 4
      for (int c = 0; c < 32; c++) {
        float4 wv = w[c];
        float4 av = *(const float4*)&sh_h1[bb][8 * c];
        s = dot8(s, wv, av);
      }
#pragma unroll 4
      for (int c = 0; c < 32; c++) {
        float4 wv = w[32 + c];
        float4 av = *(const float4*)&sh_ca[bb][8 * c];
        s = dot8(s, wv, av);
      }
      sh_ctx[bb][j] = (f16)tanhf(s);
    }
    __syncthreads();

    // S6: logit_raw = new_ctx @ Wout.T
    {
      int bb = tid >> 8, o = tid & 255;
      const float4* w = (const float4*)(wWout + (size_t)o * Hd);
      float s = 0.f;
#pragma unroll 4
      for (int c = 0; c < 32; c++) {
        float4 wv = w[c];
        float4 av = *(const float4*)&sh_ctx[bb][8 * c];
        s = dot8(s, wv, av);
      }
      sh_logit[bb][o] = (f16)s;
      sh_pi[bb][o] = s;
    }
    __syncthreads();

    // S7: pi = softmax(logit_raw), store probs output (fp32)
    {
      int bb = tid >> 8, o = tid & 255, wv = (tid >> 6) & 3, lane = tid & 63;
      float v = sh_pi[bb][o];
      float m = v;
      for (int off = 32; off; off >>= 1) m = fmaxf(m, __shfl_xor(m, off));
      if (lane == 0) sh_red[bb][wv] = m;
      __syncthreads();
      m = fmaxf(fmaxf(sh_red[bb][0], sh_red[bb][1]), fmaxf(sh_red[bb][2], sh_red[bb][3]));
      float e = __expf(v - m);
      float s = e;
      for (int off = 32; off; off >>= 1) s += __shfl_xor(s, off);
      if (lane == 0) sh_red[bb][4 + wv] = s;
      __syncthreads();
      s = sh_red[bb][4] + sh_red[bb][5] + sh_red[bb][6] + sh_red[bb][7];
      float pi = e * (1.0f / s);
      sh_pi[bb][o] = pi;
      out[(size_t)Bx * Lq + ((size_t)(b0 + bb) * Lq + t) * Od + o] = pi;
    }
    __syncthreads();

    // S8: Q = logit @ Wcrit.T + bcrit; values = sum_o pi*Q
    {
      int bb = tid >> 8, o = tid & 255, wv = (tid >> 6) & 3, lane = tid & 63;
      const float4* w = (const float4*)(wWcrit + (size_t)o * Od);
      float q = bcrit[o];
#pragma unroll 4
      for (int c = 0; c < 32; c++) {
        float4 wv4 = w[c];
        float4 lv = *(const float4*)&sh_logit[bb][8 * c];
        q = dot8(q, wv4, lv);
      }
      float pv = sh_pi[bb][o] * q;
      for (int off = 32; off; off >>= 1) pv += __shfl_xor(pv, off);
      if (lane == 0) sh_red[bb][8 + wv] = pv;
    }
    __syncthreads();
    if (tid < 2) {
      float v = sh_red[tid][8] + sh_red[tid][9] + sh_red[tid][10] + sh_red[tid][11];
      out[(size_t)Bx * Lq * (1 + Od) + (size_t)(b0 + tid) * Lq + t] = v;
    }
    __syncthreads();
  }
}

// ---------------- launcher ----------------
extern "C" void kernel_launch(void* const* d_in, const int* in_sizes, int n_in,
                              void* d_out, int out_size, void* d_ws, size_t ws_size,
                              hipStream_t stream) {
  const float* enc    = (const float*)d_in[0];
  const float* enc_h  = (const float*)d_in[1];
  const float* enc_c  = (const float*)d_in[2];
  const float* emb    = (const float*)d_in[3];
  const float* Wih0   = (const float*)d_in[4];
  const float* Whh0   = (const float*)d_in[5];
  const float* bih0   = (const float*)d_in[6];
  const float* bhh0   = (const float*)d_in[7];
  const float* Wih1   = (const float*)d_in[8];
  const float* Whh1   = (const float*)d_in[9];
  const float* bih1   = (const float*)d_in[10];
  const float* bhh1   = (const float*)d_in[11];
  const float* Wa     = (const float*)d_in[12];
  const float* Wconcat= (const float*)d_in[13];
  const float* Wout   = (const float*)d_in[14];
  const float* Wcrit  = (const float*)d_in[15];
  const float* bcrit  = (const float*)d_in[16];
  const int* actions  = (const int*)d_in[17];
  float* out = (float*)d_out;

  const size_t ENC16_B = 52428800;   // 26,214,400 f16
  const size_t W_B     = 2752512;
  const size_t T0_B    = 1048576;
  const size_t B1_B    = 4096;
  bool e16 = ws_size >= ENC16_B + W_B + T0_B + B1_B;

  char* ws = (char*)d_ws;
  f16* wsEnc16 = (f16*)ws;  // only if e16
  size_t base = e16 ? ENC16_B : 0;
  f16* wsW    = (f16*)(ws + base);
  float* wsT0 = (float*)(ws + base + W_B);
  float* wsB1 = (float*)(ws + base + W_B + T0_B);

  const f16* wWih0c   = wsW;
  const f16* wWhh0    = wsW + 262144;
  const f16* wWih1    = wsW + 524288;
  const f16* wWhh1    = wsW + 786432;
  const f16* wWconcat = wsW + 1048576;
  const f16* wWout    = wsW + 1179648;
  const f16* wWcrit   = wsW + 1245184;
  const f16* wWaT     = wsW + 1310720;

  hipLaunchKernelGGL(k_cvt_lstm, dim3(4096), dim3(256), 0, stream,
                     Wih0, Whh0, Wih1, Whh1, wsW);
  hipLaunchKernelGGL(k_cvt_small, dim3(1024), dim3(256), 0, stream,
                     Wconcat, Wout, Wcrit, Wa, (f16*)(wsW + 1048576));
  hipLaunchKernelGGL(k_bias1, dim3(4), dim3(256), 0, stream, bih1, bhh1, wsB1);
  hipLaunchKernelGGL(k_table0, dim3(64), dim3(256), 0, stream,
                     emb, Wih0, bih0, bhh0, wsT0);
  hipLaunchKernelGGL(k_actions, dim3(400), dim3(256), 0, stream, actions, out);
  if (e16) {
    hipLaunchKernelGGL(k_cvt_enc, dim3(25600), dim3(256), 0, stream, enc, wsEnc16);
    hipLaunchKernelGGL(k_seq<true>, dim3(512), dim3(512), 0, stream,
                       enc, wsEnc16, enc_h, enc_c, actions, bcrit,
                       wWih0c, wWhh0, wWih1, wWhh1, wWconcat, wWout, wWcrit, wWaT,
                       wsT0, wsB1, out);
  } else {
    hipLaunchKernelGGL(k_seq<false>, dim3(512), dim3(512), 0, stream,
                       enc, (const f16*)nullptr, enc_h, enc_c, actions, bcrit,
                       wWih0c, wWhh0, wWih1, wWhh1, wWconcat, wWout, wWcrit, wWaT,
                       wsT0, wsB1, out);
  }
}

// Round 2
// 8565.653 us; speedup vs baseline: 4.5712x; 4.5712x over previous
//
#include <hip/hip_runtime.h>

// ---------------------------------------------------------------------------
// BaseDecoderNetwork: 2-layer LSTM decoder + Luong attention, teacher-forced.
// B=1024, L=100 steps, H=O=256. All global I/O fp32.
// R4 (21.7ms): enc fp16 in ws, nontemporal enc loads, fp16 weights + dot2.
// R5 (39.2ms REGRESSION): 512x512 re-tile; grid math gave 2 blocks/CU = same
//     16 waves/CU but 2x weight traffic + 2x per-thread streams. Lesson:
//     occupancy is grid-capped at B/rows_per_block blocks; latency-bound
//     regime means traffic x2 at same concurrency = time x2.
// R6: revert to R4 geometry (256 blocks x 1024 thr, 4 rows/block) and fix the
//     actual bottleneck: weight loads are uncoalesced (thread j owns row j ->
//     64 distinct 512B rows per wave instruction, 64 lines/instr, L2 request-
//     latency bound at ~12 GB/s/CU). All fp16 weights are now pre-swizzled in
//     Phase A into wave-coalesced layout: element (j, 8c+e) at
//     [(j>>6)*32*ChunksPerRow... ] = (j>>6)*rowgroup + c*512 + (j&63)*8 + e,
//     so one wave load = 1KB contiguous. enc16 path unchanged (isolated).
// ---------------------------------------------------------------------------

#define Bx 1024
#define Lq 100
#define Hd 256
#define Od 256
#define H4 1024

typedef _Float16 f16;
typedef _Float16 half2_t __attribute__((ext_vector_type(2)));
typedef _Float16 f16x4 __attribute__((ext_vector_type(4)));
typedef unsigned int uint;
typedef uint uint4v __attribute__((ext_vector_type(4)));

__device__ __forceinline__ float fdot2(half2_t a, half2_t b, float c) {
#if __has_builtin(__builtin_amdgcn_fdot2)
  return __builtin_amdgcn_fdot2(a, b, c, false);
#else
  return c + (float)a.x * (float)b.x + (float)a.y * (float)b.y;
#endif
}
// 8-wide f16 dot: w,a are 16B chunks holding 8 halves each.
__device__ __forceinline__ float dot8(float acc, float4 w, float4 a) {
  acc = fdot2(__builtin_bit_cast(half2_t, w.x), __builtin_bit_cast(half2_t, a.x), acc);
  acc = fdot2(__builtin_bit_cast(half2_t, w.y), __builtin_bit_cast(half2_t, a.y), acc);
  acc = fdot2(__builtin_bit_cast(half2_t, w.z), __builtin_bit_cast(half2_t, a.z), acc);
  acc = fdot2(__builtin_bit_cast(half2_t, w.w), __builtin_bit_cast(half2_t, a.w), acc);
  return acc;
}
__device__ __forceinline__ float sigmf(float x) { return 1.0f / (1.0f + __expf(-x)); }

// Swizzled weight addressing (256-col matrix): element (j, k), k=8c+e:
//   idx = (j>>6)*16384 + c*512 + (j&63)*8 + e
// 512-col matrix (Wconcat): idx = (j>>6)*32768 + c*512 + (j&63)*8 + e
// A wave of 64 consecutive j reading chunk c touches 1KB contiguous.

// ---------------- Phase A kernels ----------------

// 4 LSTM weight mats (fp32) -> fp16 swizzled. seg0: Wih0 ctx-half (cols 256..511).
__global__ void k_cvt_lstm(const float* Wih0, const float* Whh0,
                           const float* Wih1, const float* Whh1, f16* dst) {
  int row = blockIdx.x, seg = row >> 10, r = row & 1023, c = threadIdx.x;
  const float* src; int stride, off;
  if (seg == 0)      { src = Wih0; stride = 512; off = 256; }
  else if (seg == 1) { src = Whh0; stride = 256; off = 0; }
  else if (seg == 2) { src = Wih1; stride = 256; off = 0; }
  else               { src = Whh1; stride = 256; off = 0; }
  size_t didx = (size_t)seg * 262144 + (size_t)(r >> 6) * 16384 +
                (size_t)(c >> 3) * 512 + (size_t)(r & 63) * 8 + (c & 7);
  dst[didx] = (f16)src[(size_t)r * stride + off + c];
}

// Wconcat(256x512), Wout, Wcrit, WaT (transposed!) -> fp16 swizzled at wsW+1048576.
__global__ void k_cvt_small(const float* Wconcat, const float* Wout,
                            const float* Wcrit, const float* Wa, f16* dst) {
  int blk = blockIdx.x, seg = blk >> 8, r = blk & 255, c = threadIdx.x;
  if (seg == 0) {
    // 512-col swizzle
    dst[(size_t)(r >> 6) * 32768 + (size_t)(c >> 3) * 512 + (r & 63) * 8 + (c & 7)] =
        (f16)Wconcat[(size_t)r * 512 + c];
    int c2 = c + 256;
    dst[(size_t)(r >> 6) * 32768 + (size_t)(c2 >> 3) * 512 + (r & 63) * 8 + (c2 & 7)] =
        (f16)Wconcat[(size_t)r * 512 + c2];
  } else if (seg == 1) {
    dst[131072 + (size_t)(r >> 6) * 16384 + (size_t)(c >> 3) * 512 + (r & 63) * 8 + (c & 7)] =
        (f16)Wout[(size_t)r * 256 + c];
  } else if (seg == 2) {
    dst[196608 + (size_t)(r >> 6) * 16384 + (size_t)(c >> 3) * 512 + (r & 63) * 8 + (c & 7)] =
        (f16)Wcrit[(size_t)r * 256 + c];
  } else {
    // WaT row = c (Wa column), WaT col = r
    dst[262144 + (size_t)(c >> 6) * 16384 + (size_t)(r >> 3) * 512 + (c & 63) * 8 + (r & 7)] =
        (f16)Wa[(size_t)r * 256 + c];
  }
}

__global__ void k_bias1(const float* bih1, const float* bhh1, float* b1) {
  int i = blockIdx.x * 256 + threadIdx.x;
  b1[i] = bih1[i] + bhh1[i];
}

__global__ void k_actions(const int* actions, float* out) {
  int i = blockIdx.x * 256 + threadIdx.x;
  out[i] = (float)actions[i];
}

// enc fp32 -> fp16 (26,214,400 elems; 4 per thread)
__global__ void k_cvt_enc(const float* enc, f16* dst) {
  size_t i = (size_t)blockIdx.x * 256 + threadIdx.x;  // float4 index
  const float4* s = (const float4*)enc;
  float4 v = s[i];
  f16x4 o = {(f16)v.x, (f16)v.y, (f16)v.z, (f16)v.w};
  *(f16x4*)(dst + 4 * i) = o;
}

// table0[a][j] = sum_k emb[a][k]*Wih0[j][k] + bih0[j] + bhh0[j]   (fp32)
__global__ void k_table0(const float* emb, const float* Wih0,
                         const float* bih0, const float* bhh0, float* t0) {
  __shared__ float shw[16][256];
  int j0 = blockIdx.x * 16, tid = threadIdx.x;
  for (int i = tid; i < 16 * 256; i += 256) {
    int r = i >> 8, c = i & 255;
    shw[r][c] = Wih0[(size_t)(j0 + r) * 512 + c];  // emb half: cols 0..255
  }
  __syncthreads();
  int a = tid;
  float acc[16];
#pragma unroll
  for (int r = 0; r < 16; r++) acc[r] = 0.f;
  for (int k = 0; k < 256; k++) {
    float e = emb[(size_t)a * 256 + k];
#pragma unroll
    for (int r = 0; r < 16; r++) acc[r] = fmaf(e, shw[r][k], acc[r]);
  }
#pragma unroll
  for (int r = 0; r < 16; r++)
    t0[(size_t)a * H4 + j0 + r] = acc[r] + bih0[j0 + r] + bhh0[j0 + r];
}

// ---------------- Phase B: fused sequential scan ----------------
// 256 blocks x 1024 threads; block owns batch rows b0..b0+3. (R4 geometry.)
template <bool E16>
__launch_bounds__(1024)
__global__ void k_seq(const float* enc, const f16* enc16,
                      const float* enc_h, const float* enc_c,
                      const int* actions, const float* bcrit,
                      const f16* wWih0c, const f16* wWhh0,
                      const f16* wWih1, const f16* wWhh1,
                      const f16* wWconcat, const f16* wWout, const f16* wWcrit,
                      const f16* wWaT,
                      const float* table0, const float* bias1, float* out) {
  const int tid = threadIdx.x;
  const int b0 = blockIdx.x * 4;

  __shared__ _Float16 sh_h0[4][264];    // fp16 activation copies (dot operands)
  __shared__ _Float16 sh_h1[4][264];
  __shared__ _Float16 sh_ctx[4][264];
  __shared__ _Float16 sh_ca[4][264];
  __shared__ _Float16 sh_logit[4][264];
  __shared__ _Float16 sh_v[4][264];     // v = h1 @ Wa (fp16 for dot2 score pass)
  __shared__ float sh_c0[4][256];       // fp32 cell-state masters
  __shared__ float sh_c1[4][256];
  __shared__ float sh_gates[4][H4];
  __shared__ float sh_sc[4][128];       // scores -> attn weights
  __shared__ float sh_pi[4][256];
  __shared__ float sh_red[4][20];
  __shared__ int sh_a[4];

  // --- init: h/c from enc_h/enc_c, ctx0 = mean_l enc ---
  {
    int bb = tid >> 8, h = tid & 255, gb = b0 + bb;
    sh_h0[bb][h] = (f16)enc_h[(size_t)(0 * Bx + gb) * Hd + h];
    sh_h1[bb][h] = (f16)enc_h[(size_t)(1 * Bx + gb) * Hd + h];
    sh_c0[bb][h] = enc_c[(size_t)(0 * Bx + gb) * Hd + h];
    sh_c1[bb][h] = enc_c[(size_t)(1 * Bx + gb) * Hd + h];
    const float* ep = enc + (size_t)gb * Lq * Hd + h;
    float s = 0.f;
#pragma unroll 4
    for (int l = 0; l < Lq; l++) s += __builtin_nontemporal_load(ep + (size_t)l * Hd);
    sh_ctx[bb][h] = (f16)(s * (1.0f / Lq));
  }
  __syncthreads();

  for (int t = 0; t < Lq; t++) {
    // S0: teacher-forced input index (x0 = 0)
    if (tid < 4) sh_a[tid] = (t == 0) ? 0 : actions[(size_t)(b0 + tid) * Lq + (t - 1)];
    __syncthreads();

    // S1: LSTM0 gates[bb][j] = table0[a] + ctx.Wih0c[j] + h0.Whh0[j]
    // Swizzled weight reads: wave of 64 consecutive j -> 1KB contiguous/load.
    {
      const int j = tid;
      const f16* w1 = wWih0c + (size_t)(j >> 6) * 16384 + (j & 63) * 8;
      const f16* w2 = wWhh0 + (size_t)(j >> 6) * 16384 + (j & 63) * 8;
      float a0 = table0[(size_t)sh_a[0] * H4 + j];
      float a1 = table0[(size_t)sh_a[1] * H4 + j];
      float a2 = table0[(size_t)sh_a[2] * H4 + j];
      float a3 = table0[(size_t)sh_a[3] * H4 + j];
#pragma unroll 4
      for (int c = 0; c < 32; c++) {
        float4 wa = *(const float4*)(w1 + (size_t)c * 512);
        float4 wb = *(const float4*)(w2 + (size_t)c * 512);
        float4 x0 = *(const float4*)&sh_ctx[0][8 * c];
        float4 x1 = *(const float4*)&sh_ctx[1][8 * c];
        float4 x2 = *(const float4*)&sh_ctx[2][8 * c];
        float4 x3 = *(const float4*)&sh_ctx[3][8 * c];
        a0 = dot8(a0, wa, x0); a1 = dot8(a1, wa, x1);
        a2 = dot8(a2, wa, x2); a3 = dot8(a3, wa, x3);
        float4 y0 = *(const float4*)&sh_h0[0][8 * c];
        float4 y1 = *(const float4*)&sh_h0[1][8 * c];
        float4 y2 = *(const float4*)&sh_h0[2][8 * c];
        float4 y3 = *(const float4*)&sh_h0[3][8 * c];
        a0 = dot8(a0, wb, y0); a1 = dot8(a1, wb, y1);
        a2 = dot8(a2, wb, y2); a3 = dot8(a3, wb, y3);
      }
      sh_gates[0][j] = a0; sh_gates[1][j] = a1;
      sh_gates[2][j] = a2; sh_gates[3][j] = a3;
    }
    __syncthreads();

    // S1b: layer-0 cell update (gate order i,f,g,o)
    {
      int bb = tid >> 8, h = tid & 255;
      float gi = sh_gates[bb][h], gf = sh_gates[bb][h + 256];
      float gg = sh_gates[bb][h + 512], go = sh_gates[bb][h + 768];
      float c = sigmf(gf) * sh_c0[bb][h] + sigmf(gi) * tanhf(gg);
      sh_c0[bb][h] = c;
      sh_h0[bb][h] = (f16)(sigmf(go) * tanhf(c));
    }
    __syncthreads();

    // S2: LSTM1 gates = bias1 + h0.Wih1[j] + h1.Whh1[j]
    {
      const int j = tid;
      const f16* w1 = wWih1 + (size_t)(j >> 6) * 16384 + (j & 63) * 8;
      const f16* w2 = wWhh1 + (size_t)(j >> 6) * 16384 + (j & 63) * 8;
      float bv = bias1[j];
      float a0 = bv, a1 = bv, a2 = bv, a3 = bv;
#pragma unroll 4
      for (int c = 0; c < 32; c++) {
        float4 wa = *(const float4*)(w1 + (size_t)c * 512);
        float4 wb = *(const float4*)(w2 + (size_t)c * 512);
        float4 x0 = *(const float4*)&sh_h0[0][8 * c];
        float4 x1 = *(const float4*)&sh_h0[1][8 * c];
        float4 x2 = *(const float4*)&sh_h0[2][8 * c];
        float4 x3 = *(const float4*)&sh_h0[3][8 * c];
        a0 = dot8(a0, wa, x0); a1 = dot8(a1, wa, x1);
        a2 = dot8(a2, wa, x2); a3 = dot8(a3, wa, x3);
        float4 y0 = *(const float4*)&sh_h1[0][8 * c];
        float4 y1 = *(const float4*)&sh_h1[1][8 * c];
        float4 y2 = *(const float4*)&sh_h1[2][8 * c];
        float4 y3 = *(const float4*)&sh_h1[3][8 * c];
        a0 = dot8(a0, wb, y0); a1 = dot8(a1, wb, y1);
        a2 = dot8(a2, wb, y2); a3 = dot8(a3, wb, y3);
      }
      sh_gates[0][j] = a0; sh_gates[1][j] = a1;
      sh_gates[2][j] = a2; sh_gates[3][j] = a3;
    }
    __syncthreads();

    // S2b: layer-1 cell update -> h1 ("out")
    {
      int bb = tid >> 8, h = tid & 255;
      float gi = sh_gates[bb][h], gf = sh_gates[bb][h + 256];
      float gg = sh_gates[bb][h + 512], go = sh_gates[bb][h + 768];
      float c = sigmf(gf) * sh_c1[bb][h] + sigmf(gi) * tanhf(gg);
      sh_c1[bb][h] = c;
      sh_h1[bb][h] = (f16)(sigmf(go) * tanhf(c));
    }
    __syncthreads();

    // S3a: v[bb][h] = sum_j h1[bb][j] * WaT[h][j]   (v = h1 @ Wa)
    {
      int bb = tid >> 8, h = tid & 255;
      const f16* w = wWaT + (size_t)(h >> 6) * 16384 + (h & 63) * 8;
      float s = 0.f;
#pragma unroll 4
      for (int c = 0; c < 32; c++) {
        float4 wv = *(const float4*)(w + (size_t)c * 512);
        float4 av = *(const float4*)&sh_h1[bb][8 * c];
        s = dot8(s, wv, av);
      }
      sh_v[bb][h] = (f16)s;
    }
    __syncthreads();

    // S3b: scores[bb][l] = v . enc[b,l,:]
    {
      int bb = tid >> 8, l = tid & 255;
      if (l < Lq) {
        float s = 0.f;
        if constexpr (E16) {
          const uint4v* ep = (const uint4v*)(enc16 + ((size_t)(b0 + bb) * Lq + l) * Hd);
#pragma unroll 4
          for (int c = 0; c < 32; c++) {
            uint4v u = __builtin_nontemporal_load(ep + c);
            float4 ev = __builtin_bit_cast(float4, u);
            float4 vv = *(const float4*)&sh_v[bb][8 * c];
            s = dot8(s, ev, vv);
          }
        } else {
          const float4* ep = (const float4*)(enc + ((size_t)(b0 + bb) * Lq + l) * Hd);
#pragma unroll 4
          for (int c = 0; c < 64; c++) {
            float4 u = ep[c];
            const f16* vv = &sh_v[bb][4 * c];
            s = fmaf(u.x, (float)vv[0], s);
            s = fmaf(u.y, (float)vv[1], s);
            s = fmaf(u.z, (float)vv[2], s);
            s = fmaf(u.w, (float)vv[3], s);
          }
        }
        sh_sc[bb][l] = s;
      }
    }
    __syncthreads();

    // S3c: softmax over l (one wave per batch row)
    if (tid < 256) {
      int bb = tid >> 6, lane = tid & 63;
      float v0 = (lane < Lq) ? sh_sc[bb][lane] : -1e30f;
      float v1 = (lane + 64 < Lq) ? sh_sc[bb][lane + 64] : -1e30f;
      float m = fmaxf(v0, v1);
      for (int off = 32; off; off >>= 1) m = fmaxf(m, __shfl_xor(m, off));
      float e0 = (lane < Lq) ? __expf(v0 - m) : 0.f;
      float e1 = (lane + 64 < Lq) ? __expf(v1 - m) : 0.f;
      float s = e0 + e1;
      for (int off = 32; off; off >>= 1) s += __shfl_xor(s, off);
      float inv = 1.0f / s;
      if (lane < Lq) sh_sc[bb][lane] = e0 * inv;
      if (lane + 64 < Lq) sh_sc[bb][lane + 64] = e1 * inv;
    }
    __syncthreads();

    // S4: ctx_att[bb][h] = sum_l attn * enc (coalesced on h)
    if constexpr (E16) {
      int bb = tid >> 8, hh = tid & 255;
      if (hh < 128) {  // each thread covers halves 2*hh, 2*hh+1
        const uint* ep = (const uint*)(enc16 + (size_t)(b0 + bb) * Lq * Hd) + hh;
        float s0 = 0.f, s1 = 0.f;
#pragma unroll 4
        for (int l = 0; l < Lq; l++) {
          uint u = __builtin_nontemporal_load(ep + (size_t)l * 128);
          half2_t hv = __builtin_bit_cast(half2_t, u);
          float a = sh_sc[bb][l];
          s0 = fmaf(a, (float)hv.x, s0);
          s1 = fmaf(a, (float)hv.y, s1);
        }
        half2_t r = {(f16)s0, (f16)s1};
        *(half2_t*)&sh_ca[bb][2 * hh] = r;
      }
    } else {
      int bb = tid >> 8, h = tid & 255;
      const float* ep = enc + (size_t)(b0 + bb) * Lq * Hd + h;
      float s = 0.f;
#pragma unroll 4
      for (int l = 0; l < Lq; l++)
        s = fmaf(sh_sc[bb][l], __builtin_nontemporal_load(ep + (size_t)l * Hd), s);
      sh_ca[bb][h] = (f16)s;
    }
    __syncthreads();

    // S5: new_ctx = tanh([h1, ctx_att] @ Wconcat.T)  (512-col swizzle)
    {
      int bb = tid >> 8, j = tid & 255;
      const f16* w = wWconcat + (size_t)(j >> 6) * 32768 + (j & 63) * 8;
      float s = 0.f;
#pragma unroll 4
      for (int c = 0; c < 32; c++) {
        float4 wv = *(const float4*)(w + (size_t)c * 512);
        float4 av = *(const float4*)&sh_h1[bb][8 * c];
        s = dot8(s, wv, av);
      }
#pragma unroll 4
      for (int c = 0; c < 32; c++) {
        float4 wv = *(const float4*)(w + (size_t)(32 + c) * 512);
        float4 av = *(const float4*)&sh_ca[bb][8 * c];
        s = dot8(s, wv, av);
      }
      sh_ctx[bb][j] = (f16)tanhf(s);
    }
    __syncthreads();

    // S6: logit_raw = new_ctx @ Wout.T
    {
      int bb = tid >> 8, o = tid & 255;
      const f16* w = wWout + (size_t)(o >> 6) * 16384 + (o & 63) * 8;
      float s = 0.f;
#pragma unroll 4
      for (int c = 0; c < 32; c++) {
        float4 wv = *(const float4*)(w + (size_t)c * 512);
        float4 av = *(const float4*)&sh_ctx[bb][8 * c];
        s = dot8(s, wv, av);
      }
      sh_logit[bb][o] = (f16)s;
      sh_pi[bb][o] = s;
    }
    __syncthreads();

    // S7: pi = softmax(logit_raw), store probs output (fp32)
    {
      int bb = tid >> 8, o = tid & 255, wv = (tid >> 6) & 3, lane = tid & 63;
      float v = sh_pi[bb][o];
      float m = v;
      for (int off = 32; off; off >>= 1) m = fmaxf(m, __shfl_xor(m, off));
      if (lane == 0) sh_red[bb][wv] = m;
      __syncthreads();
      m = fmaxf(fmaxf(sh_red[bb][0], sh_red[bb][1]), fmaxf(sh_red[bb][2], sh_red[bb][3]));
      float e = __expf(v - m);
      float s = e;
      for (int off = 32; off; off >>= 1) s += __shfl_xor(s, off);
      if (lane == 0) sh_red[bb][4 + wv] = s;
      __syncthreads();
      s = sh_red[bb][4] + sh_red[bb][5] + sh_red[bb][6] + sh_red[bb][7];
      float pi = e * (1.0f / s);
      sh_pi[bb][o] = pi;
      out[(size_t)Bx * Lq + ((size_t)(b0 + bb) * Lq + t) * Od + o] = pi;
    }
    __syncthreads();

    // S8: Q = logit @ Wcrit.T + bcrit; values = sum_o pi*Q
    {
      int bb = tid >> 8, o = tid & 255, wv = (tid >> 6) & 3, lane = tid & 63;
      const f16* w = wWcrit + (size_t)(o >> 6) * 16384 + (o & 63) * 8;
      float q = bcrit[o];
#pragma unroll 4
      for (int c = 0; c < 32; c++) {
        float4 wv4 = *(const float4*)(w + (size_t)c * 512);
        float4 lv = *(const float4*)&sh_logit[bb][8 * c];
        q = dot8(q, wv4, lv);
      }
      float pv = sh_pi[bb][o] * q;
      for (int off = 32; off; off >>= 1) pv += __shfl_xor(pv, off);
      if (lane == 0) sh_red[bb][8 + wv] = pv;
    }
    __syncthreads();
    if (tid < 4) {
      float v = sh_red[tid][8] + sh_red[tid][9] + sh_red[tid][10] + sh_red[tid][11];
      out[(size_t)Bx * Lq * (1 + Od) + (size_t)(b0 + tid) * Lq + t] = v;
    }
    __syncthreads();
  }
}

// ---------------- launcher ----------------
extern "C" void kernel_launch(void* const* d_in, const int* in_sizes, int n_in,
                              void* d_out, int out_size, void* d_ws, size_t ws_size,
                              hipStream_t stream) {
  const float* enc    = (const float*)d_in[0];
  const float* enc_h  = (const float*)d_in[1];
  const float* enc_c  = (const float*)d_in[2];
  const float* emb    = (const float*)d_in[3];
  const float* Wih0   = (const float*)d_in[4];
  const float* Whh0   = (const float*)d_in[5];
  const float* bih0   = (const float*)d_in[6];
  const float* bhh0   = (const float*)d_in[7];
  const float* Wih1   = (const float*)d_in[8];
  const float* Whh1   = (const float*)d_in[9];
  const float* bih1   = (const float*)d_in[10];
  const float* bhh1   = (const float*)d_in[11];
  const float* Wa     = (const float*)d_in[12];
  const float* Wconcat= (const float*)d_in[13];
  const float* Wout   = (const float*)d_in[14];
  const float* Wcrit  = (const float*)d_in[15];
  const float* bcrit  = (const float*)d_in[16];
  const int* actions  = (const int*)d_in[17];
  float* out = (float*)d_out;

  const size_t ENC16_B = 52428800;   // 26,214,400 f16
  const size_t W_B     = 2752512;
  const size_t T0_B    = 1048576;
  const size_t B1_B    = 4096;
  bool e16 = ws_size >= ENC16_B + W_B + T0_B + B1_B;

  char* ws = (char*)d_ws;
  f16* wsEnc16 = (f16*)ws;  // only if e16
  size_t base = e16 ? ENC16_B : 0;
  f16* wsW    = (f16*)(ws + base);
  float* wsT0 = (float*)(ws + base + W_B);
  float* wsB1 = (float*)(ws + base + W_B + T0_B);

  const f16* wWih0c   = wsW;
  const f16* wWhh0    = wsW + 262144;
  const f16* wWih1    = wsW + 524288;
  const f16* wWhh1    = wsW + 786432;
  const f16* wWconcat = wsW + 1048576;
  const f16* wWout    = wsW + 1179648;
  const f16* wWcrit   = wsW + 1245184;
  const f16* wWaT     = wsW + 1310720;

  hipLaunchKernelGGL(k_cvt_lstm, dim3(4096), dim3(256), 0, stream,
                     Wih0, Whh0, Wih1, Whh1, wsW);
  hipLaunchKernelGGL(k_cvt_small, dim3(1024), dim3(256), 0, stream,
                     Wconcat, Wout, Wcrit, Wa, (f16*)(wsW + 1048576));
  hipLaunchKernelGGL(k_bias1, dim3(4), dim3(256), 0, stream, bih1, bhh1, wsB1);
  hipLaunchKernelGGL(k_table0, dim3(64), dim3(256), 0, stream,
                     emb, Wih0, bih0, bhh0, wsT0);
  hipLaunchKernelGGL(k_actions, dim3(400), dim3(256), 0, stream, actions, out);
  if (e16) {
    hipLaunchKernelGGL(k_cvt_enc, dim3(25600), dim3(256), 0, stream, enc, wsEnc16);
    hipLaunchKernelGGL(k_seq<true>, dim3(256), dim3(1024), 0, stream,
                       enc, wsEnc16, enc_h, enc_c, actions, bcrit,
                       wWih0c, wWhh0, wWih1, wWhh1, wWconcat, wWout, wWcrit, wWaT,
                       wsT0, wsB1, out);
  } else {
    hipLaunchKernelGGL(k_seq<false>, dim3(256), dim3(1024), 0, stream,
                       enc, (const f16*)nullptr, enc_h, enc_c, actions, bcrit,
                       wWih0c, wWhh0, wWih1, wWhh1, wWconcat, wWout, wWcrit, wWaT,
                       wsT0, wsB1, out);
  }
}

// Round 3
// 6365.244 us; speedup vs baseline: 6.1515x; 1.3457x over previous
//
#include <hip/hip_runtime.h>

// ---------------------------------------------------------------------------
// BaseDecoderNetwork: 2-layer LSTM decoder + Luong attention, teacher-forced.
// B=1024, L=100 steps, H=O=256. All global I/O fp32.
// R4 (21.7ms): enc fp16 in ws, nontemporal enc loads, fp16 weights + dot2.
// R5 (39.2ms REGRESSION): 512x512 re-tile (2x traffic, same 16 waves/CU).
// R6 (8.57ms): weights pre-swizzled to wave-coalesced layout -> 1KB/wave-load.
//     VALUBusy 10->28%. FETCH_SIZE still 7.3GB/dispatch = enc16 streamed from
//     HBM every step: the nontemporal hint prevents L3 retention (52MB enc16
//     fits 256MB L3 with 5x headroom).
// R7: (a) drop NT on S3b/S4 enc16 loads -> L3-resident enc; keep NT only on
//     the one-shot fp32 init mean. (b) S4: all-1024-thread l-split (halve the
//     100-long dependent FMA chain; combine via LDS scratch in sh_gates).
// ---------------------------------------------------------------------------

#define Bx 1024
#define Lq 100
#define Hd 256
#define Od 256
#define H4 1024

typedef _Float16 f16;
typedef _Float16 half2_t __attribute__((ext_vector_type(2)));
typedef _Float16 f16x4 __attribute__((ext_vector_type(4)));
typedef unsigned int uint;
typedef uint uint4v __attribute__((ext_vector_type(4)));

__device__ __forceinline__ float fdot2(half2_t a, half2_t b, float c) {
#if __has_builtin(__builtin_amdgcn_fdot2)
  return __builtin_amdgcn_fdot2(a, b, c, false);
#else
  return c + (float)a.x * (float)b.x + (float)a.y * (float)b.y;
#endif
}
// 8-wide f16 dot: w,a are 16B chunks holding 8 halves each.
__device__ __forceinline__ float dot8(float acc, float4 w, float4 a) {
  acc = fdot2(__builtin_bit_cast(half2_t, w.x), __builtin_bit_cast(half2_t, a.x), acc);
  acc = fdot2(__builtin_bit_cast(half2_t, w.y), __builtin_bit_cast(half2_t, a.y), acc);
  acc = fdot2(__builtin_bit_cast(half2_t, w.z), __builtin_bit_cast(half2_t, a.z), acc);
  acc = fdot2(__builtin_bit_cast(half2_t, w.w), __builtin_bit_cast(half2_t, a.w), acc);
  return acc;
}
__device__ __forceinline__ float sigmf(float x) { return 1.0f / (1.0f + __expf(-x)); }

// Swizzled weight addressing (256-col matrix): element (j, k), k=8c+e:
//   idx = (j>>6)*16384 + c*512 + (j&63)*8 + e
// 512-col matrix (Wconcat): idx = (j>>6)*32768 + c*512 + (j&63)*8 + e
// A wave of 64 consecutive j reading chunk c touches 1KB contiguous.

// ---------------- Phase A kernels ----------------

// 4 LSTM weight mats (fp32) -> fp16 swizzled. seg0: Wih0 ctx-half (cols 256..511).
__global__ void k_cvt_lstm(const float* Wih0, const float* Whh0,
                           const float* Wih1, const float* Whh1, f16* dst) {
  int row = blockIdx.x, seg = row >> 10, r = row & 1023, c = threadIdx.x;
  const float* src; int stride, off;
  if (seg == 0)      { src = Wih0; stride = 512; off = 256; }
  else if (seg == 1) { src = Whh0; stride = 256; off = 0; }
  else if (seg == 2) { src = Wih1; stride = 256; off = 0; }
  else               { src = Whh1; stride = 256; off = 0; }
  size_t didx = (size_t)seg * 262144 + (size_t)(r >> 6) * 16384 +
                (size_t)(c >> 3) * 512 + (size_t)(r & 63) * 8 + (c & 7);
  dst[didx] = (f16)src[(size_t)r * stride + off + c];
}

// Wconcat(256x512), Wout, Wcrit, WaT (transposed!) -> fp16 swizzled at wsW+1048576.
__global__ void k_cvt_small(const float* Wconcat, const float* Wout,
                            const float* Wcrit, const float* Wa, f16* dst) {
  int blk = blockIdx.x, seg = blk >> 8, r = blk & 255, c = threadIdx.x;
  if (seg == 0) {
    // 512-col swizzle
    dst[(size_t)(r >> 6) * 32768 + (size_t)(c >> 3) * 512 + (r & 63) * 8 + (c & 7)] =
        (f16)Wconcat[(size_t)r * 512 + c];
    int c2 = c + 256;
    dst[(size_t)(r >> 6) * 32768 + (size_t)(c2 >> 3) * 512 + (r & 63) * 8 + (c2 & 7)] =
        (f16)Wconcat[(size_t)r * 512 + c2];
  } else if (seg == 1) {
    dst[131072 + (size_t)(r >> 6) * 16384 + (size_t)(c >> 3) * 512 + (r & 63) * 8 + (c & 7)] =
        (f16)Wout[(size_t)r * 256 + c];
  } else if (seg == 2) {
    dst[196608 + (size_t)(r >> 6) * 16384 + (size_t)(c >> 3) * 512 + (r & 63) * 8 + (c & 7)] =
        (f16)Wcrit[(size_t)r * 256 + c];
  } else {
    // WaT row = c (Wa column), WaT col = r
    dst[262144 + (size_t)(c >> 6) * 16384 + (size_t)(r >> 3) * 512 + (c & 63) * 8 + (r & 7)] =
        (f16)Wa[(size_t)r * 256 + c];
  }
}

__global__ void k_bias1(const float* bih1, const float* bhh1, float* b1) {
  int i = blockIdx.x * 256 + threadIdx.x;
  b1[i] = bih1[i] + bhh1[i];
}

__global__ void k_actions(const int* actions, float* out) {
  int i = blockIdx.x * 256 + threadIdx.x;
  out[i] = (float)actions[i];
}

// enc fp32 -> fp16 (26,214,400 elems; 4 per thread)
__global__ void k_cvt_enc(const float* enc, f16* dst) {
  size_t i = (size_t)blockIdx.x * 256 + threadIdx.x;  // float4 index
  const float4* s = (const float4*)enc;
  float4 v = s[i];
  f16x4 o = {(f16)v.x, (f16)v.y, (f16)v.z, (f16)v.w};
  *(f16x4*)(dst + 4 * i) = o;
}

// table0[a][j] = sum_k emb[a][k]*Wih0[j][k] + bih0[j] + bhh0[j]   (fp32)
__global__ void k_table0(const float* emb, const float* Wih0,
                         const float* bih0, const float* bhh0, float* t0) {
  __shared__ float shw[16][256];
  int j0 = blockIdx.x * 16, tid = threadIdx.x;
  for (int i = tid; i < 16 * 256; i += 256) {
    int r = i >> 8, c = i & 255;
    shw[r][c] = Wih0[(size_t)(j0 + r) * 512 + c];  // emb half: cols 0..255
  }
  __syncthreads();
  int a = tid;
  float acc[16];
#pragma unroll
  for (int r = 0; r < 16; r++) acc[r] = 0.f;
  for (int k = 0; k < 256; k++) {
    float e = emb[(size_t)a * 256 + k];
#pragma unroll
    for (int r = 0; r < 16; r++) acc[r] = fmaf(e, shw[r][k], acc[r]);
  }
#pragma unroll
  for (int r = 0; r < 16; r++)
    t0[(size_t)a * H4 + j0 + r] = acc[r] + bih0[j0 + r] + bhh0[j0 + r];
}

// ---------------- Phase B: fused sequential scan ----------------
// 256 blocks x 1024 threads; block owns batch rows b0..b0+3.
template <bool E16>
__launch_bounds__(1024)
__global__ void k_seq(const float* enc, const f16* enc16,
                      const float* enc_h, const float* enc_c,
                      const int* actions, const float* bcrit,
                      const f16* wWih0c, const f16* wWhh0,
                      const f16* wWih1, const f16* wWhh1,
                      const f16* wWconcat, const f16* wWout, const f16* wWcrit,
                      const f16* wWaT,
                      const float* table0, const float* bias1, float* out) {
  const int tid = threadIdx.x;
  const int b0 = blockIdx.x * 4;

  __shared__ _Float16 sh_h0[4][264];    // fp16 activation copies (dot operands)
  __shared__ _Float16 sh_h1[4][264];
  __shared__ _Float16 sh_ctx[4][264];
  __shared__ _Float16 sh_ca[4][264];
  __shared__ _Float16 sh_logit[4][264];
  __shared__ _Float16 sh_v[4][264];     // v = h1 @ Wa (fp16 for dot2 score pass)
  __shared__ float sh_c0[4][256];       // fp32 cell-state masters
  __shared__ float sh_c1[4][256];
  __shared__ float sh_gates[4][H4];     // also reused as S4 partial-sum scratch
  __shared__ float sh_sc[4][128];       // scores -> attn weights
  __shared__ float sh_pi[4][256];
  __shared__ float sh_red[4][20];
  __shared__ int sh_a[4];

  // --- init: h/c from enc_h/enc_c, ctx0 = mean_l enc (one-shot: keep NT) ---
  {
    int bb = tid >> 8, h = tid & 255, gb = b0 + bb;
    sh_h0[bb][h] = (f16)enc_h[(size_t)(0 * Bx + gb) * Hd + h];
    sh_h1[bb][h] = (f16)enc_h[(size_t)(1 * Bx + gb) * Hd + h];
    sh_c0[bb][h] = enc_c[(size_t)(0 * Bx + gb) * Hd + h];
    sh_c1[bb][h] = enc_c[(size_t)(1 * Bx + gb) * Hd + h];
    const float* ep = enc + (size_t)gb * Lq * Hd + h;
    float s = 0.f;
#pragma unroll 4
    for (int l = 0; l < Lq; l++) s += __builtin_nontemporal_load(ep + (size_t)l * Hd);
    sh_ctx[bb][h] = (f16)(s * (1.0f / Lq));
  }
  __syncthreads();

  for (int t = 0; t < Lq; t++) {
    // S0: teacher-forced input index (x0 = 0)
    if (tid < 4) sh_a[tid] = (t == 0) ? 0 : actions[(size_t)(b0 + tid) * Lq + (t - 1)];
    __syncthreads();

    // S1: LSTM0 gates[bb][j] = table0[a] + ctx.Wih0c[j] + h0.Whh0[j]
    // Swizzled weight reads: wave of 64 consecutive j -> 1KB contiguous/load.
    {
      const int j = tid;
      const f16* w1 = wWih0c + (size_t)(j >> 6) * 16384 + (j & 63) * 8;
      const f16* w2 = wWhh0 + (size_t)(j >> 6) * 16384 + (j & 63) * 8;
      float a0 = table0[(size_t)sh_a[0] * H4 + j];
      float a1 = table0[(size_t)sh_a[1] * H4 + j];
      float a2 = table0[(size_t)sh_a[2] * H4 + j];
      float a3 = table0[(size_t)sh_a[3] * H4 + j];
#pragma unroll 4
      for (int c = 0; c < 32; c++) {
        float4 wa = *(const float4*)(w1 + (size_t)c * 512);
        float4 wb = *(const float4*)(w2 + (size_t)c * 512);
        float4 x0 = *(const float4*)&sh_ctx[0][8 * c];
        float4 x1 = *(const float4*)&sh_ctx[1][8 * c];
        float4 x2 = *(const float4*)&sh_ctx[2][8 * c];
        float4 x3 = *(const float4*)&sh_ctx[3][8 * c];
        a0 = dot8(a0, wa, x0); a1 = dot8(a1, wa, x1);
        a2 = dot8(a2, wa, x2); a3 = dot8(a3, wa, x3);
        float4 y0 = *(const float4*)&sh_h0[0][8 * c];
        float4 y1 = *(const float4*)&sh_h0[1][8 * c];
        float4 y2 = *(const float4*)&sh_h0[2][8 * c];
        float4 y3 = *(const float4*)&sh_h0[3][8 * c];
        a0 = dot8(a0, wb, y0); a1 = dot8(a1, wb, y1);
        a2 = dot8(a2, wb, y2); a3 = dot8(a3, wb, y3);
      }
      sh_gates[0][j] = a0; sh_gates[1][j] = a1;
      sh_gates[2][j] = a2; sh_gates[3][j] = a3;
    }
    __syncthreads();

    // S1b: layer-0 cell update (gate order i,f,g,o)
    {
      int bb = tid >> 8, h = tid & 255;
      float gi = sh_gates[bb][h], gf = sh_gates[bb][h + 256];
      float gg = sh_gates[bb][h + 512], go = sh_gates[bb][h + 768];
      float c = sigmf(gf) * sh_c0[bb][h] + sigmf(gi) * tanhf(gg);
      sh_c0[bb][h] = c;
      sh_h0[bb][h] = (f16)(sigmf(go) * tanhf(c));
    }
    __syncthreads();

    // S2: LSTM1 gates = bias1 + h0.Wih1[j] + h1.Whh1[j]
    {
      const int j = tid;
      const f16* w1 = wWih1 + (size_t)(j >> 6) * 16384 + (j & 63) * 8;
      const f16* w2 = wWhh1 + (size_t)(j >> 6) * 16384 + (j & 63) * 8;
      float bv = bias1[j];
      float a0 = bv, a1 = bv, a2 = bv, a3 = bv;
#pragma unroll 4
      for (int c = 0; c < 32; c++) {
        float4 wa = *(const float4*)(w1 + (size_t)c * 512);
        float4 wb = *(const float4*)(w2 + (size_t)c * 512);
        float4 x0 = *(const float4*)&sh_h0[0][8 * c];
        float4 x1 = *(const float4*)&sh_h0[1][8 * c];
        float4 x2 = *(const float4*)&sh_h0[2][8 * c];
        float4 x3 = *(const float4*)&sh_h0[3][8 * c];
        a0 = dot8(a0, wa, x0); a1 = dot8(a1, wa, x1);
        a2 = dot8(a2, wa, x2); a3 = dot8(a3, wa, x3);
        float4 y0 = *(const float4*)&sh_h1[0][8 * c];
        float4 y1 = *(const float4*)&sh_h1[1][8 * c];
        float4 y2 = *(const float4*)&sh_h1[2][8 * c];
        float4 y3 = *(const float4*)&sh_h1[3][8 * c];
        a0 = dot8(a0, wb, y0); a1 = dot8(a1, wb, y1);
        a2 = dot8(a2, wb, y2); a3 = dot8(a3, wb, y3);
      }
      sh_gates[0][j] = a0; sh_gates[1][j] = a1;
      sh_gates[2][j] = a2; sh_gates[3][j] = a3;
    }
    __syncthreads();

    // S2b: layer-1 cell update -> h1 ("out")
    {
      int bb = tid >> 8, h = tid & 255;
      float gi = sh_gates[bb][h], gf = sh_gates[bb][h + 256];
      float gg = sh_gates[bb][h + 512], go = sh_gates[bb][h + 768];
      float c = sigmf(gf) * sh_c1[bb][h] + sigmf(gi) * tanhf(gg);
      sh_c1[bb][h] = c;
      sh_h1[bb][h] = (f16)(sigmf(go) * tanhf(c));
    }
    __syncthreads();

    // S3a: v[bb][h] = sum_j h1[bb][j] * WaT[h][j]   (v = h1 @ Wa)
    {
      int bb = tid >> 8, h = tid & 255;
      const f16* w = wWaT + (size_t)(h >> 6) * 16384 + (h & 63) * 8;
      float s = 0.f;
#pragma unroll 4
      for (int c = 0; c < 32; c++) {
        float4 wv = *(const float4*)(w + (size_t)c * 512);
        float4 av = *(const float4*)&sh_h1[bb][8 * c];
        s = dot8(s, wv, av);
      }
      sh_v[bb][h] = (f16)s;
    }
    __syncthreads();

    // S3b: scores[bb][l] = v . enc[b,l,:]  (normal loads: keep enc16 in L3)
    {
      int bb = tid >> 8, l = tid & 255;
      if (l < Lq) {
        float s = 0.f;
        if constexpr (E16) {
          const uint4v* ep = (const uint4v*)(enc16 + ((size_t)(b0 + bb) * Lq + l) * Hd);
#pragma unroll 4
          for (int c = 0; c < 32; c++) {
            uint4v u = ep[c];
            float4 ev = __builtin_bit_cast(float4, u);
            float4 vv = *(const float4*)&sh_v[bb][8 * c];
            s = dot8(s, ev, vv);
          }
        } else {
          const float4* ep = (const float4*)(enc + ((size_t)(b0 + bb) * Lq + l) * Hd);
#pragma unroll 4
          for (int c = 0; c < 64; c++) {
            float4 u = ep[c];
            const f16* vv = &sh_v[bb][4 * c];
            s = fmaf(u.x, (float)vv[0], s);
            s = fmaf(u.y, (float)vv[1], s);
            s = fmaf(u.z, (float)vv[2], s);
            s = fmaf(u.w, (float)vv[3], s);
          }
        }
        sh_sc[bb][l] = s;
      }
    }
    __syncthreads();

    // S3c: softmax over l (one wave per batch row)
    if (tid < 256) {
      int bb = tid >> 6, lane = tid & 63;
      float v0 = (lane < Lq) ? sh_sc[bb][lane] : -1e30f;
      float v1 = (lane + 64 < Lq) ? sh_sc[bb][lane + 64] : -1e30f;
      float m = fmaxf(v0, v1);
      for (int off = 32; off; off >>= 1) m = fmaxf(m, __shfl_xor(m, off));
      float e0 = (lane < Lq) ? __expf(v0 - m) : 0.f;
      float e1 = (lane + 64 < Lq) ? __expf(v1 - m) : 0.f;
      float s = e0 + e1;
      for (int off = 32; off; off >>= 1) s += __shfl_xor(s, off);
      float inv = 1.0f / s;
      if (lane < Lq) sh_sc[bb][lane] = e0 * inv;
      if (lane + 64 < Lq) sh_sc[bb][lane + 64] = e1 * inv;
    }
    __syncthreads();

    // S4: ctx_att[bb][h] = sum_l attn * enc.
    // R7: all 1024 threads: (bb, hh, half) with half-split over l (50 each);
    // partials in sh_gates scratch, combine by half==0 threads.
    if constexpr (E16) {
      int bb = tid >> 8, r = tid & 255;
      int hh = r & 127, half = r >> 7;
      const uint* ep = (const uint*)(enc16 + (size_t)(b0 + bb) * Lq * Hd) + hh;
      float s0 = 0.f, s1 = 0.f;
      int l0 = half * 50;
#pragma unroll 5
      for (int l = l0; l < l0 + 50; l++) {
        uint u = ep[(size_t)l * 128];
        half2_t hv = __builtin_bit_cast(half2_t, u);
        float a = sh_sc[bb][l];
        s0 = fmaf(a, (float)hv.x, s0);
        s1 = fmaf(a, (float)hv.y, s1);
      }
      sh_gates[bb][half * 512 + hh] = s0;
      sh_gates[bb][half * 512 + 128 + hh] = s1;
      __syncthreads();
      if (half == 0) {
        float r0 = sh_gates[bb][hh] + sh_gates[bb][512 + hh];
        float r1 = sh_gates[bb][128 + hh] + sh_gates[bb][512 + 128 + hh];
        half2_t rr = {(f16)r0, (f16)r1};
        *(half2_t*)&sh_ca[bb][2 * hh] = rr;
      }
    } else {
      int bb = tid >> 8, h = tid & 255;
      const float* ep = enc + (size_t)(b0 + bb) * Lq * Hd + h;
      float s = 0.f;
#pragma unroll 4
      for (int l = 0; l < Lq; l++)
        s = fmaf(sh_sc[bb][l], ep[(size_t)l * Hd], s);
      sh_ca[bb][h] = (f16)s;
    }
    __syncthreads();

    // S5: new_ctx = tanh([h1, ctx_att] @ Wconcat.T)  (512-col swizzle)
    {
      int bb = tid >> 8, j = tid & 255;
      const f16* w = wWconcat + (size_t)(j >> 6) * 32768 + (j & 63) * 8;
      float s = 0.f;
#pragma unroll 4
      for (int c = 0; c < 32; c++) {
        float4 wv = *(const float4*)(w + (size_t)c * 512);
        float4 av = *(const float4*)&sh_h1[bb][8 * c];
        s = dot8(s, wv, av);
      }
#pragma unroll 4
      for (int c = 0; c < 32; c++) {
        float4 wv = *(const float4*)(w + (size_t)(32 + c) * 512);
        float4 av = *(const float4*)&sh_ca[bb][8 * c];
        s = dot8(s, wv, av);
      }
      sh_ctx[bb][j] = (f16)tanhf(s);
    }
    __syncthreads();

    // S6: logit_raw = new_ctx @ Wout.T
    {
      int bb = tid >> 8, o = tid & 255;
      const f16* w = wWout + (size_t)(o >> 6) * 16384 + (o & 63) * 8;
      float s = 0.f;
#pragma unroll 4
      for (int c = 0; c < 32; c++) {
        float4 wv = *(const float4*)(w + (size_t)c * 512);
        float4 av = *(const float4*)&sh_ctx[bb][8 * c];
        s = dot8(s, wv, av);
      }
      sh_logit[bb][o] = (f16)s;
      sh_pi[bb][o] = s;
    }
    __syncthreads();

    // S7: pi = softmax(logit_raw), store probs output (fp32)
    {
      int bb = tid >> 8, o = tid & 255, wv = (tid >> 6) & 3, lane = tid & 63;
      float v = sh_pi[bb][o];
      float m = v;
      for (int off = 32; off; off >>= 1) m = fmaxf(m, __shfl_xor(m, off));
      if (lane == 0) sh_red[bb][wv] = m;
      __syncthreads();
      m = fmaxf(fmaxf(sh_red[bb][0], sh_red[bb][1]), fmaxf(sh_red[bb][2], sh_red[bb][3]));
      float e = __expf(v - m);
      float s = e;
      for (int off = 32; off; off >>= 1) s += __shfl_xor(s, off);
      if (lane == 0) sh_red[bb][4 + wv] = s;
      __syncthreads();
      s = sh_red[bb][4] + sh_red[bb][5] + sh_red[bb][6] + sh_red[bb][7];
      float pi = e * (1.0f / s);
      sh_pi[bb][o] = pi;
      out[(size_t)Bx * Lq + ((size_t)(b0 + bb) * Lq + t) * Od + o] = pi;
    }
    __syncthreads();

    // S8: Q = logit @ Wcrit.T + bcrit; values = sum_o pi*Q
    {
      int bb = tid >> 8, o = tid & 255, wv = (tid >> 6) & 3, lane = tid & 63;
      const f16* w = wWcrit + (size_t)(o >> 6) * 16384 + (o & 63) * 8;
      float q = bcrit[o];
#pragma unroll 4
      for (int c = 0; c < 32; c++) {
        float4 wv4 = *(const float4*)(w + (size_t)c * 512);
        float4 lv = *(const float4*)&sh_logit[bb][8 * c];
        q = dot8(q, wv4, lv);
      }
      float pv = sh_pi[bb][o] * q;
      for (int off = 32; off; off >>= 1) pv += __shfl_xor(pv, off);
      if (lane == 0) sh_red[bb][8 + wv] = pv;
    }
    __syncthreads();
    if (tid < 4) {
      float v = sh_red[tid][8] + sh_red[tid][9] + sh_red[tid][10] + sh_red[tid][11];
      out[(size_t)Bx * Lq * (1 + Od) + (size_t)(b0 + tid) * Lq + t] = v;
    }
    __syncthreads();
  }
}

// ---------------- launcher ----------------
extern "C" void kernel_launch(void* const* d_in, const int* in_sizes, int n_in,
                              void* d_out, int out_size, void* d_ws, size_t ws_size,
                              hipStream_t stream) {
  const float* enc    = (const float*)d_in[0];
  const float* enc_h  = (const float*)d_in[1];
  const float* enc_c  = (const float*)d_in[2];
  const float* emb    = (const float*)d_in[3];
  const float* Wih0   = (const float*)d_in[4];
  const float* Whh0   = (const float*)d_in[5];
  const float* bih0   = (const float*)d_in[6];
  const float* bhh0   = (const float*)d_in[7];
  const float* Wih1   = (const float*)d_in[8];
  const float* Whh1   = (const float*)d_in[9];
  const float* bih1   = (const float*)d_in[10];
  const float* bhh1   = (const float*)d_in[11];
  const float* Wa     = (const float*)d_in[12];
  const float* Wconcat= (const float*)d_in[13];
  const float* Wout   = (const float*)d_in[14];
  const float* Wcrit  = (const float*)d_in[15];
  const float* bcrit  = (const float*)d_in[16];
  const int* actions  = (const int*)d_in[17];
  float* out = (float*)d_out;

  const size_t ENC16_B = 52428800;   // 26,214,400 f16
  const size_t W_B     = 2752512;
  const size_t T0_B    = 1048576;
  const size_t B1_B    = 4096;
  bool e16 = ws_size >= ENC16_B + W_B + T0_B + B1_B;

  char* ws = (char*)d_ws;
  f16* wsEnc16 = (f16*)ws;  // only if e16
  size_t base = e16 ? ENC16_B : 0;
  f16* wsW    = (f16*)(ws + base);
  float* wsT0 = (float*)(ws + base + W_B);
  float* wsB1 = (float*)(ws + base + W_B + T0_B);

  const f16* wWih0c   = wsW;
  const f16* wWhh0    = wsW + 262144;
  const f16* wWih1    = wsW + 524288;
  const f16* wWhh1    = wsW + 786432;
  const f16* wWconcat = wsW + 1048576;
  const f16* wWout    = wsW + 1179648;
  const f16* wWcrit   = wsW + 1245184;
  const f16* wWaT     = wsW + 1310720;

  hipLaunchKernelGGL(k_cvt_lstm, dim3(4096), dim3(256), 0, stream,
                     Wih0, Whh0, Wih1, Whh1, wsW);
  hipLaunchKernelGGL(k_cvt_small, dim3(1024), dim3(256), 0, stream,
                     Wconcat, Wout, Wcrit, Wa, (f16*)(wsW + 1048576));
  hipLaunchKernelGGL(k_bias1, dim3(4), dim3(256), 0, stream, bih1, bhh1, wsB1);
  hipLaunchKernelGGL(k_table0, dim3(64), dim3(256), 0, stream,
                     emb, Wih0, bih0, bhh0, wsT0);
  hipLaunchKernelGGL(k_actions, dim3(400), dim3(256), 0, stream, actions, out);
  if (e16) {
    hipLaunchKernelGGL(k_cvt_enc, dim3(25600), dim3(256), 0, stream, enc, wsEnc16);
    hipLaunchKernelGGL(k_seq<true>, dim3(256), dim3(1024), 0, stream,
                       enc, wsEnc16, enc_h, enc_c, actions, bcrit,
                       wWih0c, wWhh0, wWih1, wWhh1, wWconcat, wWout, wWcrit, wWaT,
                       wsT0, wsB1, out);
  } else {
    hipLaunchKernelGGL(k_seq<false>, dim3(256), dim3(1024), 0, stream,
                       enc, (const f16*)nullptr, enc_h, enc_c, actions, bcrit,
                       wWih0c, wWhh0, wWih1, wWhh1, wWconcat, wWout, wWcrit, wWaT,
                       wsT0, wsB1, out);
  }
}